// Round 7
// baseline (170.242 us; speedup 1.0000x reference)
//
#include <hip/hip_runtime.h>
#include <math.h>

#define EPSV 1e-5f

typedef __attribute__((ext_vector_type(8))) _Float16 f16x8;
typedef __attribute__((ext_vector_type(4))) _Float16 f16x4;
typedef __attribute__((ext_vector_type(4))) float f32x4;

typedef __attribute__((address_space(1))) const unsigned int as1_u32;
typedef __attribute__((address_space(3))) unsigned int as3_u32;

static __device__ __forceinline__ unsigned packh2(float a, float b) {
  auto v = __builtin_amdgcn_cvt_pkrtz(a, b);  // __fp16 ext_vector(2)
  return __builtin_bit_cast(unsigned, v);
}

// ---------------- pack weights fp32 -> fp16 [4][*] (tw,pw,gw: 128x256; rw: 256x128)
__global__ __launch_bounds__(256) void pack_w(const float* __restrict__ tw,
                                              const float* __restrict__ pw,
                                              const float* __restrict__ gw,
                                              const float* __restrict__ rw,
                                              _Float16* __restrict__ w16) {
  int i = blockIdx.x * 256 + threadIdx.x;  // 131072
  const float* s = i < 32768 ? tw : (i < 65536 ? pw : (i < 98304 ? gw : rw));
  w16[i] = (_Float16)s[i & 32767];
}

// ---------------- pack x,y fp32 [n][c][p] -> fp16 transposed [src][n][p][c]
__global__ __launch_bounds__(256) void pack_xy(const float* __restrict__ x,
                                               const float* __restrict__ y,
                                               _Float16* __restrict__ xt) {
  const int n = blockIdx.y, s = blockIdx.z;
  const int g = blockIdx.x * 256 + threadIdx.x;  // 131072 per (n,s)
  const int p = g & 4095, c8 = g >> 12;          // c8 0..31
  const float* src = (s ? y : x) + ((size_t)n * 256 + c8 * 8) * 4096 + p;
  f16x8 v;
#pragma unroll
  for (int j = 0; j < 8; ++j) v[j] = (_Float16)src[(size_t)j * 4096];
  *(f16x8*)(xt + ((size_t)(s * 4 + n) * 4096 + p) * 256 + c8 * 8) = v;
}

// ---------------- projections via MFMA.
// pr 0 (theta): D=W*X -> [ci][p]; pr 1 (phi): D=X^T*W^T -> [p][ci]; pr 2 (g): D=W*X -> [ci][p]
__global__ __launch_bounds__(256) void proj_kernel(
    const _Float16* __restrict__ xt, const _Float16* __restrict__ w16,
    const float* __restrict__ tb, const float* __restrict__ pb,
    const float* __restrict__ gb, _Float16* __restrict__ th16,
    _Float16* __restrict__ ph16, _Float16* __restrict__ g16) {
  const int ptile = blockIdx.x;  // 32 tiles of 128 positions
  const int z = blockIdx.y;      // 12 = 3 pr * 4 n
  const int pr = z >> 2, n = z & 3;
  const int p0 = ptile * 128;
  const int tid = threadIdx.x, wv = tid >> 6, lane = tid & 63, lg = lane >> 4, lr = lane & 15;

  __shared__ __align__(16) char sB[65536];  // X tile [128 p][256 c] fp16, swz ((p&7)<<4)

  const int srcn = (pr == 1 ? 4 : 0) + n;
  const char* src = (const char*)(xt + ((size_t)srcn * 4096 + p0) * 256);
#pragma unroll
  for (int ps = 0; ps < 16; ++ps) {
    int L = ps * 4096 + tid * 16;
    int row = L >> 9, col = L & 511;
    __builtin_amdgcn_global_load_lds((as1_u32*)(src + (size_t)row * 512 + (col ^ ((row & 7) << 4))),
                                     (as3_u32*)(sB + L), 16, 0, 0);
  }
  const _Float16* wp = w16 + pr * 32768;
  const float* bp = pr == 0 ? tb : (pr == 1 ? pb : gb);

  if (pr != 1) {
    const int o0 = wv * 32;
    f16x8 a[2][8];
#pragma unroll
    for (int mf = 0; mf < 2; ++mf)
#pragma unroll
      for (int kc = 0; kc < 8; ++kc)
        a[mf][kc] = *(const f16x8*)(wp + (size_t)(o0 + mf * 16 + lr) * 256 + kc * 32 + lg * 8);
    __syncthreads();
    f32x4 acc[2][8];
#pragma unroll
    for (int mf = 0; mf < 2; ++mf)
#pragma unroll
      for (int nf = 0; nf < 8; ++nf) acc[mf][nf] = f32x4{0.f, 0.f, 0.f, 0.f};
#pragma unroll
    for (int kc = 0; kc < 8; ++kc) {
      f16x8 bf[8];
#pragma unroll
      for (int nf = 0; nf < 8; ++nf)
        bf[nf] = *(const f16x8*)(sB + (nf * 16 + lr) * 512 + ((kc * 64 + lg * 16) ^ ((lr & 7) << 4)));
#pragma unroll
      for (int mf = 0; mf < 2; ++mf)
#pragma unroll
        for (int nf = 0; nf < 8; ++nf)
          acc[mf][nf] = __builtin_amdgcn_mfma_f32_16x16x32_f16(a[mf][kc], bf[nf], acc[mf][nf], 0, 0, 0);
    }
    _Float16* out = (pr == 0 ? th16 : g16) + (size_t)n * 128 * 4096;
#pragma unroll
    for (int mf = 0; mf < 2; ++mf)
#pragma unroll
      for (int r = 0; r < 4; ++r) {
        int o = o0 + mf * 16 + lg * 4 + r;
        float bias = bp[o];
#pragma unroll
        for (int nf = 0; nf < 8; ++nf)
          out[(size_t)o * 4096 + p0 + nf * 16 + lr] = (_Float16)(acc[mf][nf][r] + bias);
      }
  } else {
    __syncthreads();
    const int pw0 = wv * 32;
    f32x4 acc[2][8];
#pragma unroll
    for (int mf = 0; mf < 2; ++mf)
#pragma unroll
      for (int nf = 0; nf < 8; ++nf) acc[mf][nf] = f32x4{0.f, 0.f, 0.f, 0.f};
#pragma unroll 2
    for (int kc = 0; kc < 8; ++kc) {
      f16x8 bf[8];
#pragma unroll
      for (int nf = 0; nf < 8; ++nf)
        bf[nf] = *(const f16x8*)(wp + (size_t)(nf * 16 + lr) * 256 + kc * 32 + lg * 8);
      f16x8 af[2];
#pragma unroll
      for (int mf = 0; mf < 2; ++mf)
        af[mf] = *(const f16x8*)(sB + (pw0 + mf * 16 + lr) * 512 + ((kc * 64 + lg * 16) ^ ((lr & 7) << 4)));
#pragma unroll
      for (int mf = 0; mf < 2; ++mf)
#pragma unroll
        for (int nf = 0; nf < 8; ++nf)
          acc[mf][nf] = __builtin_amdgcn_mfma_f32_16x16x32_f16(af[mf], bf[nf], acc[mf][nf], 0, 0, 0);
    }
    _Float16* out = ph16 + (size_t)n * 4096 * 128;
#pragma unroll
    for (int mf = 0; mf < 2; ++mf)
#pragma unroll
      for (int r = 0; r < 4; ++r) {
        int p = p0 + pw0 + mf * 16 + lg * 4 + r;
#pragma unroll
        for (int nf = 0; nf < 8; ++nf) {
          int o = nf * 16 + lr;
          out[(size_t)p * 128 + o] = (_Float16)(acc[mf][nf][r] + bp[o]);
        }
      }
  }
}

// ---------------- flash attention: 8 waves = 2 qsub(32q) x 4 kv-quarters
// K staged in LDS (dbuf, shared by 2 waves), G direct L2->reg, P per-wave LDS.
__global__ __launch_bounds__(512, 2) void attn_kernel(
    const _Float16* __restrict__ th16, const _Float16* __restrict__ ph16,
    const _Float16* __restrict__ g16, _Float16* __restrict__ o16) {
  const int lin = blockIdx.x;  // 256
  const int xcd = lin & 7;     // 2 XCDs per batch
  const int n = xcd >> 1;
  const int qt = ((lin >> 3) << 1) | (xcd & 1);
  const int q0 = qt * 64;
  const int tid = threadIdx.x;
  const int wv = tid >> 6, lane = tid & 63, lg = lane >> 4, lr = lane & 15;
  const int quarter = wv & 3, qsub = wv >> 2;

  // K: 4 quarters x dbuf x 16KB = 128KB ; P: 8 waves x 2 qg x 2KB = 32KB  (=160KiB)
  __shared__ __align__(16) char smem[163840];

  const _Float16* thn = th16 + (size_t)n * 128 * 4096;
  const char* phn = (const char*)(ph16 + (size_t)n * 4096 * 128);
  const char* ggn = (const char*)(g16 + (size_t)n * 128 * 4096);

  // K staging: 8 wave-instrs/iter, each 1KB (wave-uniform LDS base + lane*16)
#define STAGE(KT, B)                                                                     \
  do {                                                                                   \
    _Pragma("unroll") for (int i_ = 0; i_ < 8; ++i_) {                                   \
      const int c_ = wv * 8 + i_;                                                        \
      const int qq_ = c_ >> 4, sub_ = c_ & 15;                                           \
      const int pos_ = sub_ * 4 + (lane >> 4);                                           \
      const char* src_ = phn + (size_t)(qq_ * 1024 + (KT) * 64 + pos_) * 256 +           \
                         (((lane & 15) * 16) ^ ((pos_ & 7) << 4));                       \
      char* dst_ = smem + (qq_ * 2 + (B)) * 16384 + sub_ * 1024 + lane * 16;             \
      __builtin_amdgcn_global_load_lds((as1_u32*)src_, (as3_u32*)dst_, 16, 0, 0);        \
    }                                                                                    \
  } while (0)

  // Q fragments: B[k=ci][q], content Q[q][ci=ch*32+lg*8+j], per q-group qg
  f16x8 qf[2][4];
#pragma unroll
  for (int qg = 0; qg < 2; ++qg)
#pragma unroll
    for (int ch = 0; ch < 4; ++ch)
#pragma unroll
      for (int j = 0; j < 8; ++j)
        qf[qg][ch][j] = thn[(size_t)(ch * 32 + lg * 8 + j) * 4096 + q0 + qsub * 32 + qg * 16 + lr];

  const int swzk = (lr & 7) << 4;
  const int swzp = (lr & 15) << 3;
  char* pW = smem + 131072 + wv * 4096;

  f32x4 acc[2][8];
#pragma unroll
  for (int qg = 0; qg < 2; ++qg)
#pragma unroll
    for (int of = 0; of < 8; ++of) acc[qg][of] = f32x4{0.f, 0.f, 0.f, 0.f};
  float mrow[2] = {-INFINITY, -INFINITY}, lrow[2] = {0.f, 0.f};

  STAGE(0, 0);
  __syncthreads();

  for (int kt = 0; kt < 16; ++kt) {
    const int b = kt & 1;
    if (kt < 15) STAGE(kt + 1, b ^ 1);

    // QK: S^T[k=cf*16+lg*4+r][q=lr] per qg; each kf feeds both qg (LDS read once)
    const char* kb = smem + (quarter * 2 + b) * 16384;
    f32x4 s[4][2];
#pragma unroll
    for (int cf = 0; cf < 4; ++cf) {
      s[cf][0] = f32x4{0.f, 0.f, 0.f, 0.f};
      s[cf][1] = f32x4{0.f, 0.f, 0.f, 0.f};
    }
    __builtin_amdgcn_s_setprio(1);
#pragma unroll
    for (int cf = 0; cf < 4; ++cf) {
      const char* krow = kb + (cf * 16 + lr) * 256;
#pragma unroll
      for (int ch = 0; ch < 4; ++ch) {
        f16x8 kf = *(const f16x8*)(krow + ((ch * 64 + lg * 16) ^ swzk));
        s[cf][0] = __builtin_amdgcn_mfma_f32_16x16x32_f16(kf, qf[0][ch], s[cf][0], 0, 0, 0);
        s[cf][1] = __builtin_amdgcn_mfma_f32_16x16x32_f16(kf, qf[1][ch], s[cf][1], 0, 0, 0);
      }
    }
    __builtin_amdgcn_s_setprio(0);

    // online softmax per qg (lane-local q), write P
#pragma unroll
    for (int qg = 0; qg < 2; ++qg) {
      float mt = s[0][qg][0];
#pragma unroll
      for (int cf = 0; cf < 4; ++cf)
#pragma unroll
        for (int r = 0; r < 4; ++r) mt = fmaxf(mt, s[cf][qg][r]);
      mt = fmaxf(mt, __shfl_xor(mt, 16));
      mt = fmaxf(mt, __shfl_xor(mt, 32));
      if (!__all(mt <= mrow[qg] + 8.0f)) {  // defer-max
        float mnew = fmaxf(mrow[qg], mt);
        float sc = __expf(mrow[qg] - mnew);
#pragma unroll
        for (int of = 0; of < 8; ++of) acc[qg][of] *= sc;
        lrow[qg] *= sc;
        mrow[qg] = mnew;
      }
      float psum = 0.f;
      char* prow = pW + qg * 2048 + lr * 128;
#pragma unroll
      for (int cf = 0; cf < 4; ++cf) {
        float p0 = __expf(s[cf][qg][0] - mrow[qg]);
        float p1 = __expf(s[cf][qg][1] - mrow[qg]);
        float p2 = __expf(s[cf][qg][2] - mrow[qg]);
        float p3 = __expf(s[cf][qg][3] - mrow[qg]);
        psum += (p0 + p1) + (p2 + p3);
        unsigned long long w = (unsigned long long)packh2(p0, p1) |
                               ((unsigned long long)packh2(p2, p3) << 32);
        *(unsigned long long*)(prow + ((cf * 32 + lg * 8) ^ swzp)) = w;
      }
      psum += __shfl_xor(psum, 16);
      psum += __shfl_xor(psum, 32);
      lrow[qg] += psum;
    }

    // PV: O^T[ci][q] += G * P^T ; G loaded straight from L2 (16B contiguous)
    const size_t gk = (size_t)(quarter * 1024 + kt * 64);
    __builtin_amdgcn_s_setprio(1);
#pragma unroll
    for (int kc = 0; kc < 2; ++kc) {
      const int b0 = kc * 64 + lg * 16;
      char* pr0 = pW + lr * 128;
      char* pr1 = pW + 2048 + lr * 128;
      unsigned long long a0 = *(unsigned long long*)(pr0 + (b0 ^ swzp));
      unsigned long long a1 = *(unsigned long long*)(pr0 + ((b0 + 8) ^ swzp));
      unsigned long long b0q = *(unsigned long long*)(pr1 + (b0 ^ swzp));
      unsigned long long b1q = *(unsigned long long*)(pr1 + ((b0 + 8) ^ swzp));
      f16x8 pf0, pf1;
      {
        unsigned* u = (unsigned*)&pf0;
        u[0] = (unsigned)a0; u[1] = (unsigned)(a0 >> 32);
        u[2] = (unsigned)a1; u[3] = (unsigned)(a1 >> 32);
      }
      {
        unsigned* u = (unsigned*)&pf1;
        u[0] = (unsigned)b0q; u[1] = (unsigned)(b0q >> 32);
        u[2] = (unsigned)b1q; u[3] = (unsigned)(b1q >> 32);
      }
#pragma unroll
      for (int of = 0; of < 8; ++of) {
        f16x8 gf = *(const f16x8*)(ggn + ((size_t)(of * 16 + lr) * 4096 + gk + kc * 32 + lg * 8) * 2);
        acc[0][of] = __builtin_amdgcn_mfma_f32_16x16x32_f16(gf, pf0, acc[0][of], 0, 0, 0);
        acc[1][of] = __builtin_amdgcn_mfma_f32_16x16x32_f16(gf, pf1, acc[1][of], 0, 0, 0);
      }
    }
    __builtin_amdgcn_s_setprio(0);
    __syncthreads();  // drains stage(kt+1); both qsub waves done with buf b
  }

  // ----- 4-way split-K merge (per-lane q = lr per qg)
  float* fsm = (float*)smem;
  if (quarter != 0) {
    const int pi = (quarter - 1) * 2 + qsub;  // 0..5
    float* aslot = fsm + pi * 4096 + lane * 64;
#pragma unroll
    for (int qg = 0; qg < 2; ++qg)
#pragma unroll
      for (int of = 0; of < 8; ++of) *(f32x4*)(aslot + (qg * 8 + of) * 4) = acc[qg][of];
    float* ml = fsm + 24576 + (pi * 64 + lane) * 4;
    ml[0] = mrow[0]; ml[1] = lrow[0]; ml[2] = mrow[1]; ml[3] = lrow[1];
  }
  __syncthreads();
  if (quarter == 0) {
#pragma unroll
    for (int qg = 0; qg < 2; ++qg) {
      float mm = mrow[qg];
      float pm[3], pl[3];
#pragma unroll
      for (int p_ = 0; p_ < 3; ++p_) {
        const float* ml = fsm + 24576 + ((p_ * 2 + qsub) * 64 + lane) * 4;
        pm[p_] = ml[qg * 2];
        pl[p_] = ml[qg * 2 + 1];
        mm = fmaxf(mm, pm[p_]);
      }
      float a0 = __expf(mrow[qg] - mm);
      float l = lrow[qg] * a0;
      float aa[3];
#pragma unroll
      for (int p_ = 0; p_ < 3; ++p_) {
        aa[p_] = __expf(pm[p_] - mm);
        l += pl[p_] * aa[p_];
      }
      float inv = 1.0f / l;
#pragma unroll
      for (int of = 0; of < 8; ++of) {
        f32x4 v = acc[qg][of] * a0;
#pragma unroll
        for (int p_ = 0; p_ < 3; ++p_) {
          const f32x4 pv = *(const f32x4*)(fsm + (p_ * 2 + qsub) * 4096 + lane * 64 + (qg * 8 + of) * 4);
          v += pv * aa[p_];
        }
        acc[qg][of] = v * inv;
      }
    }
    // transpose O^T -> [q][ci] through LDS, store fp16 coalesced
    float* ep = fsm + 28672 + qsub * 2112;  // 16 rows x 132 f32
    char* on = (char*)(o16 + (size_t)n * 4096 * 128);
#pragma unroll
    for (int qg = 0; qg < 2; ++qg) {
#pragma unroll
      for (int of = 0; of < 8; ++of)
#pragma unroll
        for (int r = 0; r < 4; ++r) ep[lr * 132 + of * 16 + lg * 4 + r] = acc[qg][of][r];
#pragma unroll
      for (int it = 0; it < 4; ++it) {
        int e = lane + it * 64;
        int qq = e >> 4, c8 = e & 15;
        f32x4 va = *(const f32x4*)(ep + qq * 132 + c8 * 8);
        f32x4 vb = *(const f32x4*)(ep + qq * 132 + c8 * 8 + 4);
        f16x8 h;
#pragma unroll
        for (int j = 0; j < 4; ++j) { h[j] = (_Float16)va[j]; h[4 + j] = (_Float16)vb[j]; }
        *(f16x8*)(on + (size_t)(q0 + qsub * 32 + qg * 16 + qq) * 256 + c8 * 16) = h;
      }
    }
  }
#undef STAGE
}

// ---------------- rec projection (MFMA) -> fp16 + per-block BN partial stats
__global__ __launch_bounds__(256) void rec_kernel(
    const _Float16* __restrict__ o16, const _Float16* __restrict__ rw16,
    const float* __restrict__ rb, _Float16* __restrict__ rec16,
    float* __restrict__ partial) {
  const int pblk = blockIdx.x;  // 128 tiles of 32 positions
  const int n = blockIdx.y;
  const int p0 = pblk * 32;
  const int blin = n * 128 + pblk;  // 0..511
  const int tid = threadIdx.x, wv = tid >> 6, lane = tid & 63, lg = lane >> 4, lr = lane & 15;
  __shared__ __align__(16) char sB[8192];  // O tile [32 pos][128 ci] fp16, swizzled
  const char* o16n = (const char*)(o16 + (size_t)n * 4096 * 128);
  const char* srcb = o16n + (size_t)p0 * 256 + (tid >> 4) * 256 +
                     (((tid & 15) * 16) ^ (((tid >> 4) & 7) << 4));
  __builtin_amdgcn_global_load_lds((as1_u32*)srcb, (as3_u32*)(sB + tid * 16), 16, 0, 0);
  __builtin_amdgcn_global_load_lds((as1_u32*)(srcb + 4096), (as3_u32*)(sB + 4096 + tid * 16), 16, 0, 0);

  const int wc0 = wv * 64;
  f16x8 a[4][4];
#pragma unroll
  for (int mf = 0; mf < 4; ++mf)
#pragma unroll
    for (int kc = 0; kc < 4; ++kc)
      a[mf][kc] = *(const f16x8*)(rw16 + (size_t)(wc0 + mf * 16 + lr) * 128 + kc * 32 + lg * 8);
  __syncthreads();

  f32x4 acc[4][2];
#pragma unroll
  for (int mf = 0; mf < 4; ++mf) {
    acc[mf][0] = f32x4{0.f, 0.f, 0.f, 0.f};
    acc[mf][1] = f32x4{0.f, 0.f, 0.f, 0.f};
  }
  const int xorv = (lr & 7) << 4;
#pragma unroll
  for (int kc = 0; kc < 4; ++kc) {
    int cb = (kc * 64 + lg * 16) ^ xorv;
    f16x8 b0 = *(const f16x8*)(sB + lr * 256 + cb);
    f16x8 b1 = *(const f16x8*)(sB + (16 + lr) * 256 + cb);
#pragma unroll
    for (int mf = 0; mf < 4; ++mf) {
      acc[mf][0] = __builtin_amdgcn_mfma_f32_16x16x32_f16(a[mf][kc], b0, acc[mf][0], 0, 0, 0);
      acc[mf][1] = __builtin_amdgcn_mfma_f32_16x16x32_f16(a[mf][kc], b1, acc[mf][1], 0, 0, 0);
    }
  }
  float* pslot = partial + (size_t)blin * 512;
#pragma unroll
  for (int mf = 0; mf < 4; ++mf)
#pragma unroll
    for (int r = 0; r < 4; ++r) {
      int c = wc0 + mf * 16 + lg * 4 + r;
      float bias = rb[c];
      float v0 = acc[mf][0][r] + bias;
      float v1 = acc[mf][1][r] + bias;
      rec16[((size_t)n * 256 + c) * 4096 + p0 + lr] = (_Float16)v0;
      rec16[((size_t)n * 256 + c) * 4096 + p0 + 16 + lr] = (_Float16)v1;
      float s = v0 + v1, qd = v0 * v0 + v1 * v1;
      s += __shfl_xor(s, 1); qd += __shfl_xor(qd, 1);
      s += __shfl_xor(s, 2); qd += __shfl_xor(qd, 2);
      s += __shfl_xor(s, 4); qd += __shfl_xor(qd, 4);
      s += __shfl_xor(s, 8); qd += __shfl_xor(qd, 8);
      if (lr == 0) {
        pslot[c] = s;
        pslot[256 + c] = qd;
      }
    }
}

// ---------------- reduce per-block partials -> stats[512]
__global__ __launch_bounds__(256) void stats_reduce(const float* __restrict__ partial,
                                                    float* __restrict__ stats) {
  const int j = blockIdx.x * 256 + threadIdx.x;  // 0..511
  float s = 0.f;
#pragma unroll 8
  for (int b = 0; b < 512; ++b) s += partial[(size_t)b * 512 + j];
  stats[j] = s;
}

// ---------------- BN apply + residual (reads fp16 rec result)
__global__ __launch_bounds__(256) void bn_kernel(
    const float* __restrict__ x, const float* __restrict__ gamma,
    const float* __restrict__ beta, const float* __restrict__ stats,
    const _Float16* __restrict__ rec16, float* __restrict__ out) {
  const size_t i4 = (size_t)blockIdx.x * 256 + threadIdx.x;
  const int c = (int)((i4 >> 10) & 255);
  const float inv = 1.f / 16384.f;
  const float mean = stats[c] * inv;
  const float var = stats[256 + c] * inv - mean * mean;
  const float gm = gamma[c] * rsqrtf(var + EPSV);
  const float bt = beta[c];
  f16x4 r4 = ((const f16x4*)rec16)[i4];
  float4 xv = ((const float4*)x)[i4];
  float4 o;
  o.x = xv.x + ((float)r4[0] - mean) * gm + bt;
  o.y = xv.y + ((float)r4[1] - mean) * gm + bt;
  o.z = xv.z + ((float)r4[2] - mean) * gm + bt;
  o.w = xv.w + ((float)r4[3] - mean) * gm + bt;
  ((float4*)out)[i4] = o;
}

extern "C" void kernel_launch(void* const* d_in, const int* in_sizes, int n_in,
                              void* d_out, int out_size, void* d_ws, size_t ws_size,
                              hipStream_t stream) {
  const float* x  = (const float*)d_in[0];
  const float* y  = (const float*)d_in[1];
  const float* tw = (const float*)d_in[2];
  const float* tb = (const float*)d_in[3];
  const float* pw = (const float*)d_in[4];
  const float* pb = (const float*)d_in[5];
  const float* gw = (const float*)d_in[6];
  const float* gb = (const float*)d_in[7];
  const float* rw = (const float*)d_in[8];
  const float* rb = (const float*)d_in[9];
  const float* gamma = (const float*)d_in[10];
  const float* beta  = (const float*)d_in[11];
  float* out = (float*)d_out;
  _Float16* xt    = (_Float16*)d_ws;        // 16MB [2][4][4096][256]
  _Float16* w16   = xt + 8388608;           // 256KB [4][32768]
  _Float16* th16  = w16 + 131072;           // 4MB [n][ci][p]
  _Float16* ph16  = th16 + 2097152;         // 4MB [n][p][ci]
  _Float16* g16   = ph16 + 2097152;         // 4MB [n][ci][p]
  _Float16* o16   = g16 + 2097152;          // 4MB [n][q][ci]
  _Float16* rec16 = o16 + 2097152;          // 8MB [n][c][p]
  float* partial  = (float*)(rec16 + 4194304);  // 1MB [512][512]
  float* stats    = partial + 262144;           // 512 f32
  _Float16* rw16 = w16 + 98304;
  pack_w<<<dim3(512), 256, 0, stream>>>(tw, pw, gw, rw, w16);
  pack_xy<<<dim3(512, 4, 2), 256, 0, stream>>>(x, y, xt);
  proj_kernel<<<dim3(32, 12), 256, 0, stream>>>(xt, w16, tb, pb, gb, th16, ph16, g16);
  attn_kernel<<<dim3(256), 512, 0, stream>>>(th16, ph16, g16, o16);
  rec_kernel<<<dim3(128, 4), 256, 0, stream>>>(o16, rw16, rb, rec16, partial);
  stats_reduce<<<dim3(2), 256, 0, stream>>>(partial, stats);
  bn_kernel<<<dim3(4096), 256, 0, stream>>>(x, gamma, beta, stats, rec16, out);
}

// Round 8
// 170.003 us; speedup vs baseline: 1.0014x; 1.0014x over previous
//
#include <hip/hip_runtime.h>
#include <math.h>

#define EPSV 1e-5f

typedef __attribute__((ext_vector_type(8))) _Float16 f16x8;
typedef __attribute__((ext_vector_type(4))) _Float16 f16x4;
typedef __attribute__((ext_vector_type(4))) float f32x4;

typedef __attribute__((address_space(1))) const unsigned int as1_u32;
typedef __attribute__((address_space(3))) unsigned int as3_u32;

static __device__ __forceinline__ unsigned packh2(float a, float b) {
  auto v = __builtin_amdgcn_cvt_pkrtz(a, b);  // __fp16 ext_vector(2)
  return __builtin_bit_cast(unsigned, v);
}

// ---------------- pack weights fp32 -> fp16 [4][*] (tw,pw,gw: 128x256; rw: 256x128)
__global__ __launch_bounds__(256) void pack_w(const float* __restrict__ tw,
                                              const float* __restrict__ pw,
                                              const float* __restrict__ gw,
                                              const float* __restrict__ rw,
                                              _Float16* __restrict__ w16) {
  int i = blockIdx.x * 256 + threadIdx.x;  // 131072
  const float* s = i < 32768 ? tw : (i < 65536 ? pw : (i < 98304 ? gw : rw));
  w16[i] = (_Float16)s[i & 32767];
}

// ---------------- pack x,y fp32 [n][c][p] -> fp16 transposed [src][n][p][c]
__global__ __launch_bounds__(256) void pack_xy(const float* __restrict__ x,
                                               const float* __restrict__ y,
                                               _Float16* __restrict__ xt) {
  const int n = blockIdx.y, s = blockIdx.z;
  const int g = blockIdx.x * 256 + threadIdx.x;  // 131072 per (n,s)
  const int p = g & 4095, c8 = g >> 12;          // c8 0..31
  const float* src = (s ? y : x) + ((size_t)n * 256 + c8 * 8) * 4096 + p;
  f16x8 v;
#pragma unroll
  for (int j = 0; j < 8; ++j) v[j] = (_Float16)src[(size_t)j * 4096];
  *(f16x8*)(xt + ((size_t)(s * 4 + n) * 4096 + p) * 256 + c8 * 8) = v;
}

// ---------------- projections via MFMA.
// pr 0 (theta): D=W*X -> [ci][p]; pr 1 (phi): D=X^T*W^T -> [p][ci]; pr 2 (g): D=W*X -> [ci][p]
__global__ __launch_bounds__(256) void proj_kernel(
    const _Float16* __restrict__ xt, const _Float16* __restrict__ w16,
    const float* __restrict__ tb, const float* __restrict__ pb,
    const float* __restrict__ gb, _Float16* __restrict__ th16,
    _Float16* __restrict__ ph16, _Float16* __restrict__ g16) {
  const int ptile = blockIdx.x;  // 32 tiles of 128 positions
  const int z = blockIdx.y;      // 12 = 3 pr * 4 n
  const int pr = z >> 2, n = z & 3;
  const int p0 = ptile * 128;
  const int tid = threadIdx.x, wv = tid >> 6, lane = tid & 63, lg = lane >> 4, lr = lane & 15;

  __shared__ __align__(16) char sB[65536];  // X tile [128 p][256 c] fp16, swz ((p&7)<<4)

  const int srcn = (pr == 1 ? 4 : 0) + n;
  const char* src = (const char*)(xt + ((size_t)srcn * 4096 + p0) * 256);
#pragma unroll
  for (int ps = 0; ps < 16; ++ps) {
    int L = ps * 4096 + tid * 16;
    int row = L >> 9, col = L & 511;
    __builtin_amdgcn_global_load_lds((as1_u32*)(src + (size_t)row * 512 + (col ^ ((row & 7) << 4))),
                                     (as3_u32*)(sB + L), 16, 0, 0);
  }
  const _Float16* wp = w16 + pr * 32768;
  const float* bp = pr == 0 ? tb : (pr == 1 ? pb : gb);

  if (pr != 1) {
    const int o0 = wv * 32;
    f16x8 a[2][8];
#pragma unroll
    for (int mf = 0; mf < 2; ++mf)
#pragma unroll
      for (int kc = 0; kc < 8; ++kc)
        a[mf][kc] = *(const f16x8*)(wp + (size_t)(o0 + mf * 16 + lr) * 256 + kc * 32 + lg * 8);
    __syncthreads();
    f32x4 acc[2][8];
#pragma unroll
    for (int mf = 0; mf < 2; ++mf)
#pragma unroll
      for (int nf = 0; nf < 8; ++nf) acc[mf][nf] = f32x4{0.f, 0.f, 0.f, 0.f};
#pragma unroll
    for (int kc = 0; kc < 8; ++kc) {
      f16x8 bf[8];
#pragma unroll
      for (int nf = 0; nf < 8; ++nf)
        bf[nf] = *(const f16x8*)(sB + (nf * 16 + lr) * 512 + ((kc * 64 + lg * 16) ^ ((lr & 7) << 4)));
#pragma unroll
      for (int mf = 0; mf < 2; ++mf)
#pragma unroll
        for (int nf = 0; nf < 8; ++nf)
          acc[mf][nf] = __builtin_amdgcn_mfma_f32_16x16x32_f16(a[mf][kc], bf[nf], acc[mf][nf], 0, 0, 0);
    }
    _Float16* out = (pr == 0 ? th16 : g16) + (size_t)n * 128 * 4096;
#pragma unroll
    for (int mf = 0; mf < 2; ++mf)
#pragma unroll
      for (int r = 0; r < 4; ++r) {
        int o = o0 + mf * 16 + lg * 4 + r;
        float bias = bp[o];
#pragma unroll
        for (int nf = 0; nf < 8; ++nf)
          out[(size_t)o * 4096 + p0 + nf * 16 + lr] = (_Float16)(acc[mf][nf][r] + bias);
      }
  } else {
    __syncthreads();
    const int pw0 = wv * 32;
    f32x4 acc[2][8];
#pragma unroll
    for (int mf = 0; mf < 2; ++mf)
#pragma unroll
      for (int nf = 0; nf < 8; ++nf) acc[mf][nf] = f32x4{0.f, 0.f, 0.f, 0.f};
#pragma unroll 2
    for (int kc = 0; kc < 8; ++kc) {
      f16x8 bf[8];
#pragma unroll
      for (int nf = 0; nf < 8; ++nf)
        bf[nf] = *(const f16x8*)(wp + (size_t)(nf * 16 + lr) * 256 + kc * 32 + lg * 8);
      f16x8 af[2];
#pragma unroll
      for (int mf = 0; mf < 2; ++mf)
        af[mf] = *(const f16x8*)(sB + (pw0 + mf * 16 + lr) * 512 + ((kc * 64 + lg * 16) ^ ((lr & 7) << 4)));
#pragma unroll
      for (int mf = 0; mf < 2; ++mf)
#pragma unroll
        for (int nf = 0; nf < 8; ++nf)
          acc[mf][nf] = __builtin_amdgcn_mfma_f32_16x16x32_f16(af[mf], bf[nf], acc[mf][nf], 0, 0, 0);
    }
    _Float16* out = ph16 + (size_t)n * 4096 * 128;
#pragma unroll
    for (int mf = 0; mf < 2; ++mf)
#pragma unroll
      for (int r = 0; r < 4; ++r) {
        int p = p0 + pw0 + mf * 16 + lg * 4 + r;
#pragma unroll
        for (int nf = 0; nf < 8; ++nf) {
          int o = nf * 16 + lr;
          out[(size_t)p * 128 + o] = (_Float16)(acc[mf][nf][r] + bp[o]);
        }
      }
  }
}

// ---------------- flash attention: 8 waves = 2 qsub(32q) x 4 kv-quarters
// K staged in LDS (dbuf); G prefetched global->reg BEFORE staging (vmcnt order!).
__global__ __launch_bounds__(512, 2) void attn_kernel(
    const _Float16* __restrict__ th16, const _Float16* __restrict__ ph16,
    const _Float16* __restrict__ g16, _Float16* __restrict__ o16) {
  const int lin = blockIdx.x;  // 256
  const int xcd = lin & 7;     // 2 XCDs per batch
  const int n = xcd >> 1;
  const int qt = ((lin >> 3) << 1) | (xcd & 1);
  const int q0 = qt * 64;
  const int tid = threadIdx.x;
  const int wv = tid >> 6, lane = tid & 63, lg = lane >> 4, lr = lane & 15;
  const int quarter = wv & 3, qsub = wv >> 2;

  // K: 4 quarters x dbuf x 16KB = 128KB ; P: 8 waves x 2 qg x 2KB = 32KB  (=160KiB)
  __shared__ __align__(16) char smem[163840];

  const _Float16* thn = th16 + (size_t)n * 128 * 4096;
  const char* phn = (const char*)(ph16 + (size_t)n * 4096 * 128);
  const char* ggn = (const char*)(g16 + (size_t)n * 128 * 4096);

  // K staging: 8 wave-instrs/iter, each 1KB (wave-uniform LDS base + lane*16)
#define STAGE(KT, B)                                                                     \
  do {                                                                                   \
    _Pragma("unroll") for (int i_ = 0; i_ < 8; ++i_) {                                   \
      const int c_ = wv * 8 + i_;                                                        \
      const int qq_ = c_ >> 4, sub_ = c_ & 15;                                           \
      const int pos_ = sub_ * 4 + (lane >> 4);                                           \
      const char* src_ = phn + (size_t)(qq_ * 1024 + (KT) * 64 + pos_) * 256 +           \
                         (((lane & 15) * 16) ^ ((pos_ & 7) << 4));                       \
      char* dst_ = smem + (qq_ * 2 + (B)) * 16384 + sub_ * 1024 + lane * 16;             \
      __builtin_amdgcn_global_load_lds((as1_u32*)src_, (as3_u32*)dst_, 16, 0, 0);        \
    }                                                                                    \
  } while (0)

  // Q fragments: B[k=ci][q], content Q[q][ci=ch*32+lg*8+j], per q-group qg
  f16x8 qf[2][4];
#pragma unroll
  for (int qg = 0; qg < 2; ++qg)
#pragma unroll
    for (int ch = 0; ch < 4; ++ch)
#pragma unroll
      for (int j = 0; j < 8; ++j)
        qf[qg][ch][j] = thn[(size_t)(ch * 32 + lg * 8 + j) * 4096 + q0 + qsub * 32 + qg * 16 + lr];

  const int swzk = (lr & 7) << 4;
  const int swzp = (lr & 15) << 3;
  char* pW = smem + 131072 + wv * 4096;

  f32x4 acc[2][8];
#pragma unroll
  for (int qg = 0; qg < 2; ++qg)
#pragma unroll
    for (int of = 0; of < 8; ++of) acc[qg][of] = f32x4{0.f, 0.f, 0.f, 0.f};
  float mrow[2] = {-INFINITY, -INFINITY}, lrow[2] = {0.f, 0.f};

  STAGE(0, 0);
  __syncthreads();

  for (int kt = 0; kt < 16; ++kt) {
    const int b = kt & 1;

    // (1) G prefetch for THIS tile into registers — issued BEFORE staging so the
    //     PV-side wait is vmcnt(8) and next-tile staging stays in flight (T14/T4).
    const size_t gk = (size_t)(quarter * 1024 + kt * 64);
    f16x8 gfr[2][8];
#pragma unroll
    for (int kc = 0; kc < 2; ++kc)
#pragma unroll
      for (int of = 0; of < 8; ++of)
        gfr[kc][of] = *(const f16x8*)(ggn + ((size_t)(of * 16 + lr) * 4096 + gk + kc * 32 + lg * 8) * 2);
    __builtin_amdgcn_sched_barrier(0);  // pin: G loads issue first

    // (2) stage next K tile (newer in vmcnt queue than G loads)
    if (kt < 15) STAGE(kt + 1, b ^ 1);
    __builtin_amdgcn_sched_barrier(0);  // pin: staging issued before compute

    // (3) QK: S^T[k=cf*16+lg*4+r][q=lr] per qg; each kf feeds both qg
    const char* kb = smem + (quarter * 2 + b) * 16384;
    f32x4 s[4][2];
#pragma unroll
    for (int cf = 0; cf < 4; ++cf) {
      s[cf][0] = f32x4{0.f, 0.f, 0.f, 0.f};
      s[cf][1] = f32x4{0.f, 0.f, 0.f, 0.f};
    }
    __builtin_amdgcn_s_setprio(1);
#pragma unroll
    for (int cf = 0; cf < 4; ++cf) {
      const char* krow = kb + (cf * 16 + lr) * 256;
#pragma unroll
      for (int ch = 0; ch < 4; ++ch) {
        f16x8 kf = *(const f16x8*)(krow + ((ch * 64 + lg * 16) ^ swzk));
        s[cf][0] = __builtin_amdgcn_mfma_f32_16x16x32_f16(kf, qf[0][ch], s[cf][0], 0, 0, 0);
        s[cf][1] = __builtin_amdgcn_mfma_f32_16x16x32_f16(kf, qf[1][ch], s[cf][1], 0, 0, 0);
      }
    }
    __builtin_amdgcn_s_setprio(0);

    // (4) online softmax per qg (lane-local q), write P
#pragma unroll
    for (int qg = 0; qg < 2; ++qg) {
      float mt = s[0][qg][0];
#pragma unroll
      for (int cf = 0; cf < 4; ++cf)
#pragma unroll
        for (int r = 0; r < 4; ++r) mt = fmaxf(mt, s[cf][qg][r]);
      mt = fmaxf(mt, __shfl_xor(mt, 16));
      mt = fmaxf(mt, __shfl_xor(mt, 32));
      if (!__all(mt <= mrow[qg] + 8.0f)) {  // defer-max
        float mnew = fmaxf(mrow[qg], mt);
        float sc = __expf(mrow[qg] - mnew);
#pragma unroll
        for (int of = 0; of < 8; ++of) acc[qg][of] *= sc;
        lrow[qg] *= sc;
        mrow[qg] = mnew;
      }
      float psum = 0.f;
      char* prow = pW + qg * 2048 + lr * 128;
#pragma unroll
      for (int cf = 0; cf < 4; ++cf) {
        float p0 = __expf(s[cf][qg][0] - mrow[qg]);
        float p1 = __expf(s[cf][qg][1] - mrow[qg]);
        float p2 = __expf(s[cf][qg][2] - mrow[qg]);
        float p3 = __expf(s[cf][qg][3] - mrow[qg]);
        psum += (p0 + p1) + (p2 + p3);
        unsigned long long w = (unsigned long long)packh2(p0, p1) |
                               ((unsigned long long)packh2(p2, p3) << 32);
        *(unsigned long long*)(prow + ((cf * 32 + lg * 8) ^ swzp)) = w;
      }
      psum += __shfl_xor(psum, 16);
      psum += __shfl_xor(psum, 32);
      lrow[qg] += psum;
    }

    // (5) PV: O^T[ci][q] += G * P^T with register G
    __builtin_amdgcn_s_setprio(1);
#pragma unroll
    for (int kc = 0; kc < 2; ++kc) {
      const int b0 = kc * 64 + lg * 16;
      char* pr0 = pW + lr * 128;
      char* pr1 = pW + 2048 + lr * 128;
      unsigned long long a0 = *(unsigned long long*)(pr0 + (b0 ^ swzp));
      unsigned long long a1 = *(unsigned long long*)(pr0 + ((b0 + 8) ^ swzp));
      unsigned long long b0q = *(unsigned long long*)(pr1 + (b0 ^ swzp));
      unsigned long long b1q = *(unsigned long long*)(pr1 + ((b0 + 8) ^ swzp));
      f16x8 pf0, pf1;
      {
        unsigned* u = (unsigned*)&pf0;
        u[0] = (unsigned)a0; u[1] = (unsigned)(a0 >> 32);
        u[2] = (unsigned)a1; u[3] = (unsigned)(a1 >> 32);
      }
      {
        unsigned* u = (unsigned*)&pf1;
        u[0] = (unsigned)b0q; u[1] = (unsigned)(b0q >> 32);
        u[2] = (unsigned)b1q; u[3] = (unsigned)(b1q >> 32);
      }
#pragma unroll
      for (int of = 0; of < 8; ++of) {
        acc[0][of] = __builtin_amdgcn_mfma_f32_16x16x32_f16(gfr[kc][of], pf0, acc[0][of], 0, 0, 0);
        acc[1][of] = __builtin_amdgcn_mfma_f32_16x16x32_f16(gfr[kc][of], pf1, acc[1][of], 0, 0, 0);
      }
    }
    __builtin_amdgcn_s_setprio(0);
    __syncthreads();  // drains stage(kt+1); both qsub waves done with buf b
  }

  // ----- 4-way split-K merge (per-lane q = lr per qg)
  float* fsm = (float*)smem;
  if (quarter != 0) {
    const int pi = (quarter - 1) * 2 + qsub;  // 0..5
    float* aslot = fsm + pi * 4096 + lane * 64;
#pragma unroll
    for (int qg = 0; qg < 2; ++qg)
#pragma unroll
      for (int of = 0; of < 8; ++of) *(f32x4*)(aslot + (qg * 8 + of) * 4) = acc[qg][of];
    float* ml = fsm + 24576 + (pi * 64 + lane) * 4;
    ml[0] = mrow[0]; ml[1] = lrow[0]; ml[2] = mrow[1]; ml[3] = lrow[1];
  }
  __syncthreads();
  if (quarter == 0) {
#pragma unroll
    for (int qg = 0; qg < 2; ++qg) {
      float mm = mrow[qg];
      float pm[3], pl[3];
#pragma unroll
      for (int p_ = 0; p_ < 3; ++p_) {
        const float* ml = fsm + 24576 + ((p_ * 2 + qsub) * 64 + lane) * 4;
        pm[p_] = ml[qg * 2];
        pl[p_] = ml[qg * 2 + 1];
        mm = fmaxf(mm, pm[p_]);
      }
      float a0 = __expf(mrow[qg] - mm);
      float l = lrow[qg] * a0;
      float aa[3];
#pragma unroll
      for (int p_ = 0; p_ < 3; ++p_) {
        aa[p_] = __expf(pm[p_] - mm);
        l += pl[p_] * aa[p_];
      }
      float inv = 1.0f / l;
#pragma unroll
      for (int of = 0; of < 8; ++of) {
        f32x4 v = acc[qg][of] * a0;
#pragma unroll
        for (int p_ = 0; p_ < 3; ++p_) {
          const f32x4 pv = *(const f32x4*)(fsm + (p_ * 2 + qsub) * 4096 + lane * 64 + (qg * 8 + of) * 4);
          v += pv * aa[p_];
        }
        acc[qg][of] = v * inv;
      }
    }
    // transpose O^T -> [q][ci] through LDS, store fp16 coalesced
    float* ep = fsm + 28672 + qsub * 2112;  // 16 rows x 132 f32
    char* on = (char*)(o16 + (size_t)n * 4096 * 128);
#pragma unroll
    for (int qg = 0; qg < 2; ++qg) {
#pragma unroll
      for (int of = 0; of < 8; ++of)
#pragma unroll
        for (int r = 0; r < 4; ++r) ep[lr * 132 + of * 16 + lg * 4 + r] = acc[qg][of][r];
#pragma unroll
      for (int it = 0; it < 4; ++it) {
        int e = lane + it * 64;
        int qq = e >> 4, c8 = e & 15;
        f32x4 va = *(const f32x4*)(ep + qq * 132 + c8 * 8);
        f32x4 vb = *(const f32x4*)(ep + qq * 132 + c8 * 8 + 4);
        f16x8 h;
#pragma unroll
        for (int j = 0; j < 4; ++j) { h[j] = (_Float16)va[j]; h[4 + j] = (_Float16)vb[j]; }
        *(f16x8*)(on + (size_t)(q0 + qsub * 32 + qg * 16 + qq) * 256 + c8 * 16) = h;
      }
    }
  }
#undef STAGE
}

// ---------------- rec projection (MFMA) -> fp16 + per-block BN partial stats
__global__ __launch_bounds__(256) void rec_kernel(
    const _Float16* __restrict__ o16, const _Float16* __restrict__ rw16,
    const float* __restrict__ rb, _Float16* __restrict__ rec16,
    float* __restrict__ partial) {
  const int pblk = blockIdx.x;  // 128 tiles of 32 positions
  const int n = blockIdx.y;
  const int p0 = pblk * 32;
  const int blin = n * 128 + pblk;  // 0..511
  const int tid = threadIdx.x, wv = tid >> 6, lane = tid & 63, lg = lane >> 4, lr = lane & 15;
  __shared__ __align__(16) char sB[8192];  // O tile [32 pos][128 ci] fp16, swizzled
  const char* o16n = (const char*)(o16 + (size_t)n * 4096 * 128);
  const char* srcb = o16n + (size_t)p0 * 256 + (tid >> 4) * 256 +
                     (((tid & 15) * 16) ^ (((tid >> 4) & 7) << 4));
  __builtin_amdgcn_global_load_lds((as1_u32*)srcb, (as3_u32*)(sB + tid * 16), 16, 0, 0);
  __builtin_amdgcn_global_load_lds((as1_u32*)(srcb + 4096), (as3_u32*)(sB + 4096 + tid * 16), 16, 0, 0);

  const int wc0 = wv * 64;
  f16x8 a[4][4];
#pragma unroll
  for (int mf = 0; mf < 4; ++mf)
#pragma unroll
    for (int kc = 0; kc < 4; ++kc)
      a[mf][kc] = *(const f16x8*)(rw16 + (size_t)(wc0 + mf * 16 + lr) * 128 + kc * 32 + lg * 8);
  __syncthreads();

  f32x4 acc[4][2];
#pragma unroll
  for (int mf = 0; mf < 4; ++mf) {
    acc[mf][0] = f32x4{0.f, 0.f, 0.f, 0.f};
    acc[mf][1] = f32x4{0.f, 0.f, 0.f, 0.f};
  }
  const int xorv = (lr & 7) << 4;
#pragma unroll
  for (int kc = 0; kc < 4; ++kc) {
    int cb = (kc * 64 + lg * 16) ^ xorv;
    f16x8 b0 = *(const f16x8*)(sB + lr * 256 + cb);
    f16x8 b1 = *(const f16x8*)(sB + (16 + lr) * 256 + cb);
#pragma unroll
    for (int mf = 0; mf < 4; ++mf) {
      acc[mf][0] = __builtin_amdgcn_mfma_f32_16x16x32_f16(a[mf][kc], b0, acc[mf][0], 0, 0, 0);
      acc[mf][1] = __builtin_amdgcn_mfma_f32_16x16x32_f16(a[mf][kc], b1, acc[mf][1], 0, 0, 0);
    }
  }
  float* pslot = partial + (size_t)blin * 512;
#pragma unroll
  for (int mf = 0; mf < 4; ++mf)
#pragma unroll
    for (int r = 0; r < 4; ++r) {
      int c = wc0 + mf * 16 + lg * 4 + r;
      float bias = rb[c];
      float v0 = acc[mf][0][r] + bias;
      float v1 = acc[mf][1][r] + bias;
      rec16[((size_t)n * 256 + c) * 4096 + p0 + lr] = (_Float16)v0;
      rec16[((size_t)n * 256 + c) * 4096 + p0 + 16 + lr] = (_Float16)v1;
      float s = v0 + v1, qd = v0 * v0 + v1 * v1;
      s += __shfl_xor(s, 1); qd += __shfl_xor(qd, 1);
      s += __shfl_xor(s, 2); qd += __shfl_xor(qd, 2);
      s += __shfl_xor(s, 4); qd += __shfl_xor(qd, 4);
      s += __shfl_xor(s, 8); qd += __shfl_xor(qd, 8);
      if (lr == 0) {
        pslot[c] = s;
        pslot[256 + c] = qd;
      }
    }
}

// ---------------- reduce per-block partials -> stats[512]
__global__ __launch_bounds__(256) void stats_reduce(const float* __restrict__ partial,
                                                    float* __restrict__ stats) {
  const int j = blockIdx.x * 256 + threadIdx.x;  // 0..511
  float s = 0.f;
#pragma unroll 8
  for (int b = 0; b < 512; ++b) s += partial[(size_t)b * 512 + j];
  stats[j] = s;
}

// ---------------- BN apply + residual (reads fp16 rec result)
__global__ __launch_bounds__(256) void bn_kernel(
    const float* __restrict__ x, const float* __restrict__ gamma,
    const float* __restrict__ beta, const float* __restrict__ stats,
    const _Float16* __restrict__ rec16, float* __restrict__ out) {
  const size_t i4 = (size_t)blockIdx.x * 256 + threadIdx.x;
  const int c = (int)((i4 >> 10) & 255);
  const float inv = 1.f / 16384.f;
  const float mean = stats[c] * inv;
  const float var = stats[256 + c] * inv - mean * mean;
  const float gm = gamma[c] * rsqrtf(var + EPSV);
  const float bt = beta[c];
  f16x4 r4 = ((const f16x4*)rec16)[i4];
  float4 xv = ((const float4*)x)[i4];
  float4 o;
  o.x = xv.x + ((float)r4[0] - mean) * gm + bt;
  o.y = xv.y + ((float)r4[1] - mean) * gm + bt;
  o.z = xv.z + ((float)r4[2] - mean) * gm + bt;
  o.w = xv.w + ((float)r4[3] - mean) * gm + bt;
  ((float4*)out)[i4] = o;
}

extern "C" void kernel_launch(void* const* d_in, const int* in_sizes, int n_in,
                              void* d_out, int out_size, void* d_ws, size_t ws_size,
                              hipStream_t stream) {
  const float* x  = (const float*)d_in[0];
  const float* y  = (const float*)d_in[1];
  const float* tw = (const float*)d_in[2];
  const float* tb = (const float*)d_in[3];
  const float* pw = (const float*)d_in[4];
  const float* pb = (const float*)d_in[5];
  const float* gw = (const float*)d_in[6];
  const float* gb = (const float*)d_in[7];
  const float* rw = (const float*)d_in[8];
  const float* rb = (const float*)d_in[9];
  const float* gamma = (const float*)d_in[10];
  const float* beta  = (const float*)d_in[11];
  float* out = (float*)d_out;
  _Float16* xt    = (_Float16*)d_ws;        // 16MB [2][4][4096][256]
  _Float16* w16   = xt + 8388608;           // 256KB [4][32768]
  _Float16* th16  = w16 + 131072;           // 4MB [n][ci][p]
  _Float16* ph16  = th16 + 2097152;         // 4MB [n][p][ci]
  _Float16* g16   = ph16 + 2097152;         // 4MB [n][ci][p]
  _Float16* o16   = g16 + 2097152;          // 4MB [n][q][ci]
  _Float16* rec16 = o16 + 2097152;          // 8MB [n][c][p]
  float* partial  = (float*)(rec16 + 4194304);  // 1MB [512][512]
  float* stats    = partial + 262144;           // 512 f32
  _Float16* rw16 = w16 + 98304;
  pack_w<<<dim3(512), 256, 0, stream>>>(tw, pw, gw, rw, w16);
  pack_xy<<<dim3(512, 4, 2), 256, 0, stream>>>(x, y, xt);
  proj_kernel<<<dim3(32, 12), 256, 0, stream>>>(xt, w16, tb, pb, gb, th16, ph16, g16);
  attn_kernel<<<dim3(256), 512, 0, stream>>>(th16, ph16, g16, o16);
  rec_kernel<<<dim3(128, 4), 256, 0, stream>>>(o16, rw16, rb, rec16, partial);
  stats_reduce<<<dim3(2), 256, 0, stream>>>(partial, stats);
  bn_kernel<<<dim3(4096), 256, 0, stream>>>(x, gamma, beta, stats, rec16, out);
}